// Round 2
// baseline (669.842 us; speedup 1.0000x reference)
//
#include <hip/hip_runtime.h>

// KnowledgeGNN forward. Sizes fixed per reference.
#define Dd   64
#define Tt   4096
#define Nn   20000
#define Mm   24096      // T + N
#define Ee   100000
#define Rr   50
#define TOK  768

typedef unsigned short u16;   // raw bf16

__device__ __forceinline__ float b2f(u16 v){ return __uint_as_float(((unsigned)v)<<16); }
__device__ __forceinline__ u16 f2bf(float f){
  unsigned u = __float_as_uint(f);
  u += 0x7FFFu + ((u>>16)&1u);          // round-to-nearest-even
  return (u16)(u>>16);
}
// flag-dispatched float load: isf32 ? fp32[i] : bf16[i]
__device__ __forceinline__ float ldf(const void* p, size_t i, int isf32){
  return isf32 ? ((const float*)p)[i] : b2f(((const u16*)p)[i]);
}
__device__ __forceinline__ void stf(void* p, size_t i, float v, int isf32){
  if(isf32) ((float*)p)[i] = v; else ((u16*)p)[i] = f2bf(v);
}
__device__ __forceinline__ float waveRed(float v){
  #pragma unroll
  for(int o=32;o;o>>=1) v += __shfl_xor(v,o,64);
  return v;
}

// Detect fp32 vs bf16 from token_embeddings (random N(0,1) values).
// If bf16 stream: low u16 of each u32 is a bf16 value -> exponent bits
// (lo>>7)&0xFF cluster near 0x7F. If fp32: low u16 = low mantissa bits,
// uniform -> exponent-looking field uniform over [0,255].
__global__ void k_detect(const unsigned* __restrict__ tok, int* __restrict__ flag){
  if(blockIdx.x==0 && threadIdx.x==0){
    int cnt = 0;
    for(int i=0;i<256;i++){
      unsigned lo = tok[i] & 0xFFFFu;
      unsigned e = (lo>>7)&0xFFu;
      if(e >= 0x68u && e <= 0x90u) cnt++;
    }
    flag[0] = (cnt < 128) ? 1 : 0;   // 1 => fp32 inputs/outputs
  }
}

// x[0:T] = token_embeddings @ w_lin1 + b_lin1
__global__ void k_tok(const void* __restrict__ tokemb, const void* __restrict__ w,
                      const void* __restrict__ b, float* __restrict__ x,
                      const int* __restrict__ flg){
  const int isf32 = flg[0];
  int t = blockIdx.x*256 + threadIdx.x;        // T*64 threads
  int row = t>>6, d = t&63;
  float acc = ldf(b, d, isf32);
  if(isf32){
    const float* ar = (const float*)tokemb + (size_t)row*TOK;
    const float* wp = (const float*)w;
    #pragma unroll 8
    for(int k=0;k<TOK;k++) acc += ar[k] * wp[k*Dd + d];
  }else{
    const u16* ar = (const u16*)tokemb + (size_t)row*TOK;
    const u16* wp = (const u16*)w;
    #pragma unroll 8
    for(int k=0;k<TOK;k++) acc += b2f(ar[k]) * b2f(wp[k*Dd + d]);
  }
  x[row*Dd + d] = acc;
}

// x[T:M] = kg_emb[node_ids]
__global__ void k_nodes(const int* __restrict__ ids, const void* __restrict__ kg,
                        float* __restrict__ x, const int* __restrict__ flg){
  const int isf32 = flg[0];
  int t = blockIdx.x*256 + threadIdx.x;        // N*64 threads
  int i = t>>6, d = t&63;
  x[(Tt+i)*Dd + d] = ldf(kg, (size_t)ids[i]*Dd + d, isf32);
}

// rel_id[e] = index of the 1 in one-hot edge_attr row
__global__ void k_relid(const void* __restrict__ ea, int* __restrict__ relid,
                        const int* __restrict__ flg){
  const int isf32 = flg[0];
  int e = blockIdx.x*256 + threadIdx.x;
  if(e >= Ee) return;
  size_t base = (size_t)e*Rr;
  int r = 0;
  for(int k=0;k<Rr;k++){ if(ldf(ea, base+k, isf32) > 0.5f){ r = k; break; } }
  relid[e] = r;
}

// W[r] = relu(rel_emb[r] @ w_e2 + b_e2), r<50, flat [r*4096 + d*64 + o]
__global__ void k_W(const void* __restrict__ rel, const void* __restrict__ w2,
                    const void* __restrict__ b2, float* __restrict__ W,
                    const int* __restrict__ flg){
  const int isf32 = flg[0];
  int t = blockIdx.x*256 + threadIdx.x;        // R*4096 threads
  int r = t>>12, j = t&4095;
  float acc = ldf(b2, j, isf32);
  if(isf32){
    const float* rp = (const float*)rel + r*Dd;
    const float* wp = (const float*)w2;
    #pragma unroll 8
    for(int d=0;d<Dd;d++) acc += rp[d] * wp[d*4096 + j];
  }else{
    const u16* rp = (const u16*)rel + r*Dd;
    const u16* wp = (const u16*)w2;
    #pragma unroll 8
    for(int d=0;d<Dd;d++) acc += b2f(rp[d]) * b2f(wp[d*4096 + j]);
  }
  W[t] = acc > 0.f ? acc : 0.f;
}

// u_r[d] = sum_o W[r][d][o] * att_w[64+o]  (for both layers)
__global__ void k_U(const float* __restrict__ W, const void* __restrict__ a1w,
                    const void* __restrict__ a2w, float* __restrict__ U1,
                    float* __restrict__ U2, const int* __restrict__ flg){
  const int isf32 = flg[0];
  int t = blockIdx.x*256 + threadIdx.x;        // R*64
  if(t >= Rr*Dd) return;
  const float* wp = W + (t>>6)*4096 + (t&63)*Dd;
  float s1 = 0.f, s2 = 0.f;
  #pragma unroll 8
  for(int o=0;o<Dd;o++){
    float w = wp[o];
    s1 += w*ldf(a1w, Dd+o, isf32);
    s2 += w*ldf(a2w, Dd+o, isf32);
  }
  U1[t] = s1; U2[t] = s2;
}

// p[i] = x[i] . att_w[0:64]   (one wave per row)
__global__ void k_p(const float* __restrict__ x, const void* __restrict__ aw,
                    float* __restrict__ p, const int* __restrict__ flg){
  const int isf32 = flg[0];
  int gid = blockIdx.x*256 + threadIdx.x;
  int i = gid>>6, lane = gid&63;
  float v = x[i*Dd + lane] * ldf(aw, lane, isf32);
  v = waveRed(v);
  if(lane==0) p[i] = v;
}

// expa[e] = exp(p[dst] + x[src].u_rel + att_b); block partial sums of expa
__global__ void k_att(const float* __restrict__ x, const int* __restrict__ ei,
                      const int* __restrict__ relid, const float* __restrict__ U,
                      const float* __restrict__ p, const void* __restrict__ ab,
                      float* __restrict__ expa, float* __restrict__ part,
                      const int* __restrict__ flg){
  const int isf32 = flg[0];
  __shared__ float sw[4];
  int wid = threadIdx.x>>6, lane = threadIdx.x&63;
  int e = blockIdx.x*4 + wid;                  // 25000 blocks exactly
  int src = ei[e], dst = ei[Ee+e], r = relid[e];
  float v = x[src*Dd + lane] * U[r*Dd + lane];
  v = waveRed(v);
  if(lane==0){
    float ex = expf(v + p[dst] + ldf(ab, 0, isf32));
    expa[e] = ex;
    sw[wid] = ex;
  }
  __syncthreads();
  if(threadIdx.x==0) part[blockIdx.x] = sw[0]+sw[1]+sw[2]+sw[3];
}

// single-block reduce of n partials -> out[0]
__global__ void k_redsum(const float* __restrict__ part, int n, float* __restrict__ out){
  __shared__ float sr[4];
  float s = 0.f;
  for(int i=threadIdx.x;i<n;i+=256) s += part[i];
  s = waveRed(s);
  if((threadIdx.x&63)==0) sr[threadIdx.x>>6] = s;
  __syncthreads();
  if(threadIdx.x==0) out[0] = sr[0]+sr[1]+sr[2]+sr[3];
}

// y = x @ root + bias
__global__ void k_root(const float* __restrict__ x, const void* __restrict__ root,
                       const void* __restrict__ bias, float* __restrict__ y,
                       const int* __restrict__ flg){
  const int isf32 = flg[0];
  int t = blockIdx.x*256 + threadIdx.x;        // M*64
  int i = t>>6, d = t&63;
  float acc = ldf(bias, d, isf32);
  const float* xr = x + i*Dd;
  if(isf32){
    const float* rp = (const float*)root;
    #pragma unroll 8
    for(int k=0;k<Dd;k++) acc += xr[k]*rp[k*Dd + d];
  }else{
    const u16* rp = (const u16*)root;
    #pragma unroll 8
    for(int k=0;k<Dd;k++) acc += xr[k]*b2f(rp[k*Dd + d]);
  }
  y[t] = acc;
}

// y[dst] += x[src] * (expa[e]/S)
__global__ void k_scatter(const float* __restrict__ x, const int* __restrict__ ei,
                          const float* __restrict__ expa, const float* __restrict__ S,
                          float* __restrict__ y){
  int wid = threadIdx.x>>6, lane = threadIdx.x&63;
  int e = blockIdx.x*4 + wid;
  float alpha = expa[e] / S[0];
  int src = ei[e], dst = ei[Ee+e];
  atomicAdd(&y[dst*Dd + lane], x[src*Dd + lane]*alpha);
}

__global__ void k_relu(float* __restrict__ h){
  int t = blockIdx.x*256 + threadIdx.x;        // M*64
  float v = h[t];
  h[t] = v > 0.f ? v : 0.f;
}

// out[i,j] = fx[i] . w_lin2[:,j] + b_lin2[j]  (dtype-flag store)
__global__ void k_out(const float* __restrict__ fx, const void* __restrict__ w,
                      const void* __restrict__ b, void* __restrict__ out,
                      const int* __restrict__ flg){
  const int isf32 = flg[0];
  __shared__ float row[Dd];
  int i = blockIdx.x;
  if(threadIdx.x < Dd) row[threadIdx.x] = fx[i*Dd + threadIdx.x];
  __syncthreads();
  int j = blockIdx.y*256 + threadIdx.x;
  float acc = ldf(b, j, isf32);
  if(isf32){
    const float* wp = (const float*)w;
    #pragma unroll
    for(int k=0;k<Dd;k++) acc += row[k]*wp[k*TOK + j];
  }else{
    const u16* wp = (const u16*)w;
    #pragma unroll
    for(int k=0;k<Dd;k++) acc += row[k]*b2f(wp[k*TOK + j]);
  }
  stf(out, (size_t)i*TOK + j, acc, isf32);
}

// masked MSE partials over edges (wave per edge, grid-stride)
__global__ void k_kge(const float* __restrict__ fx, const int* __restrict__ ei,
                      const int* __restrict__ relid, const void* __restrict__ rel,
                      float* __restrict__ part, const int* __restrict__ flg){
  const int isf32 = flg[0];
  __shared__ float sr[4];
  int wid = threadIdx.x>>6, lane = threadIdx.x&63;
  int gw = blockIdx.x*4 + wid;                 // 512 blocks -> 2048 waves
  float acc = 0.f;
  for(int e=gw; e<Ee; e+=2048){
    int r = relid[e];
    if(r < 47){
      int src = ei[e], dst = ei[Ee+e];
      float d = fx[src*Dd + lane] + ldf(rel, r*Dd + lane, isf32) - fx[dst*Dd + lane];
      acc += d*d;
    }
  }
  acc = waveRed(acc);
  if(lane==0) sr[wid] = acc;
  __syncthreads();
  if(threadIdx.x==0) part[blockIdx.x] = sr[0]+sr[1]+sr[2]+sr[3];
}

// node-type CE partials (thread per node)
__global__ void k_nt(const float* __restrict__ fx, const int* __restrict__ lab,
                     const void* __restrict__ wnt, const void* __restrict__ bnt,
                     float* __restrict__ part, const int* __restrict__ flg){
  const int isf32 = flg[0];
  __shared__ float sr[4];
  int i = blockIdx.x*256 + threadIdx.x;
  float contrib = 0.f;
  if(i < Mm){
    const float* r = fx + i*Dd;
    float l0 = ldf(bnt,0,isf32), l1 = ldf(bnt,1,isf32), l2 = ldf(bnt,2,isf32);
    #pragma unroll 8
    for(int k=0;k<Dd;k++){
      float f = r[k];
      l0 += f*ldf(wnt, k*3+0, isf32);
      l1 += f*ldf(wnt, k*3+1, isf32);
      l2 += f*ldf(wnt, k*3+2, isf32);
    }
    float mx = fmaxf(l0, fmaxf(l1,l2));
    float lse = logf(expf(l0-mx)+expf(l1-mx)+expf(l2-mx)) + mx;
    int lb = lab[i];
    float lp = (lb==0 ? l0 : (lb==1 ? l1 : l2)) - lse;
    contrib = -lp;
  }
  float s = waveRed(contrib);
  if((threadIdx.x&63)==0) sr[threadIdx.x>>6] = s;
  __syncthreads();
  if(threadIdx.x==0) part[blockIdx.x] = sr[0]+sr[1]+sr[2]+sr[3];
}

// reduce loss partials, write the 2 scalar outputs at element offset M*TOK
__global__ void k_final(const float* __restrict__ kgep, const float* __restrict__ ntp,
                        void* __restrict__ out, const int* __restrict__ flg){
  const int isf32 = flg[0];
  __shared__ float sa[4], sb[4];
  float s = 0.f, t = 0.f;
  for(int i=threadIdx.x;i<512;i+=256) s += kgep[i];
  for(int i=threadIdx.x;i<95;i+=256)  t += ntp[i];
  s = waveRed(s); t = waveRed(t);
  if((threadIdx.x&63)==0){ sa[threadIdx.x>>6] = s; sb[threadIdx.x>>6] = t; }
  __syncthreads();
  if(threadIdx.x==0){
    size_t base = (size_t)Mm*TOK;
    stf(out, base+0, (sa[0]+sa[1]+sa[2]+sa[3]) / (float)(Ee*Dd), isf32);
    stf(out, base+1, (sb[0]+sb[1]+sb[2]+sb[3]) / (float)Mm, isf32);
  }
}

extern "C" void kernel_launch(void* const* d_in, const int* in_sizes, int n_in,
                              void* d_out, int out_size, void* d_ws, size_t ws_size,
                              hipStream_t stream) {
  const int* node_ids = (const int*)d_in[0];
  const int* ei       = (const int*)d_in[1];
  const void* eattr   = d_in[2];
  const void* tokemb  = d_in[3];
  const int* labels   = (const int*)d_in[4];
  const void* kg      = d_in[5];
  const void* rel     = d_in[6];
  const void* w_e2    = d_in[7];
  const void* b_e2    = d_in[8];
  const void* a1w     = d_in[9];
  const void* a1b     = d_in[10];
  const void* root1   = d_in[11];
  const void* bias1   = d_in[12];
  const void* a2w     = d_in[13];
  const void* a2b     = d_in[14];
  const void* root2   = d_in[15];
  const void* bias2   = d_in[16];
  const void* wlin1   = d_in[17];
  const void* blin1   = d_in[18];
  const void* wlin2   = d_in[19];
  const void* blin2   = d_in[20];
  const void* wnt     = d_in[21];
  const void* bnt     = d_in[22];

  float* ws = (float*)d_ws;
  float* x    = ws;                       // M*64
  float* h    = x  + (size_t)Mm*Dd;       // M*64
  float* fx   = h  + (size_t)Mm*Dd;       // M*64
  float* W    = fx + (size_t)Mm*Dd;       // 50*4096
  float* U1   = W  + Rr*4096;             // 3200
  float* U2   = U1 + Rr*Dd;               // 3200
  float* expa = U2 + Rr*Dd;               // E
  float* p    = expa + Ee;                // M
  int*   relid= (int*)(p + Mm);           // E
  float* part = (float*)(relid + Ee);     // 25000
  float* kgep = part + 25000;             // 512
  float* ntp  = kgep + 512;               // 95 (padded to 128)
  float* red  = ntp + 128;                // 2
  int*   flagp= (int*)(red + 2);          // 1

  // ---- dtype detection ----
  k_detect<<<1, 64, 0, stream>>>((const unsigned*)tokemb, flagp);

  // ---- stage 0: embeddings + edge-net precompute ----
  k_tok  <<<Tt*Dd/256, 256, 0, stream>>>(tokemb, wlin1, blin1, x, flagp);
  k_nodes<<<Nn*Dd/256, 256, 0, stream>>>(node_ids, kg, x, flagp);
  k_relid<<<(Ee+255)/256, 256, 0, stream>>>(eattr, relid, flagp);
  k_W    <<<Rr*4096/256, 256, 0, stream>>>(rel, w_e2, b_e2, W, flagp);
  k_U    <<<(Rr*Dd+255)/256, 256, 0, stream>>>(W, a1w, a2w, U1, U2, flagp);

  // ---- layer 1: x -> h ----
  k_p      <<<Mm*Dd/256, 256, 0, stream>>>(x, a1w, p, flagp);
  k_att    <<<Ee/4, 256, 0, stream>>>(x, ei, relid, U1, p, a1b, expa, part, flagp);
  k_redsum <<<1, 256, 0, stream>>>(part, Ee/4, red);
  k_root   <<<Mm*Dd/256, 256, 0, stream>>>(x, root1, bias1, h, flagp);
  k_scatter<<<Ee/4, 256, 0, stream>>>(x, ei, expa, red, h);
  k_relu   <<<Mm*Dd/256, 256, 0, stream>>>(h);

  // ---- layer 2: h -> fx ----
  k_p      <<<Mm*Dd/256, 256, 0, stream>>>(h, a2w, p, flagp);
  k_att    <<<Ee/4, 256, 0, stream>>>(h, ei, relid, U2, p, a2b, expa, part, flagp);
  k_redsum <<<1, 256, 0, stream>>>(part, Ee/4, red+1);
  k_root   <<<Mm*Dd/256, 256, 0, stream>>>(h, root2, bias2, fx, flagp);
  k_scatter<<<Ee/4, 256, 0, stream>>>(h, ei, expa, red+1, fx);

  // ---- outputs ----
  dim3 og(Mm, TOK/256);
  k_out  <<<og, 256, 0, stream>>>(fx, wlin2, blin2, d_out, flagp);
  k_kge  <<<512, 256, 0, stream>>>(fx, ei, relid, rel, kgep, flagp);
  k_nt   <<<(Mm+255)/256, 256, 0, stream>>>(fx, labels, wnt, bnt, ntp, flagp);
  k_final<<<1, 256, 0, stream>>>(kgep, ntp, d_out, flagp);
}

// Round 3
// 473.015 us; speedup vs baseline: 1.4161x; 1.4161x over previous
//
#include <hip/hip_runtime.h>

// KnowledgeGNN forward, fp32 I/O (confirmed by round-2 WRITE_SIZE). Sizes fixed.
#define Dd   64
#define Tt   4096
#define Nn   20000
#define Mm   24096      // T + N
#define Ee   100000
#define Rr   50
#define TOK  768

__device__ __forceinline__ float waveRed(float v){
  #pragma unroll
  for(int o=32;o;o>>=1) v += __shfl_xor(v,o,64);
  return v;
}
__device__ __forceinline__ float4 relu4(float4 v){
  v.x=fmaxf(v.x,0.f); v.y=fmaxf(v.y,0.f); v.z=fmaxf(v.z,0.f); v.w=fmaxf(v.w,0.f);
  return v;
}

// x[0:T] = tokemb @ w_lin1 + b_lin1.  16 rows/block (4 rows/wave), K tiled by 64.
__global__ __launch_bounds__(256) void k_tok(const float* __restrict__ A,
    const float* __restrict__ w, const float* __restrict__ b, float* __restrict__ x){
  __shared__ float ws[64][Dd];
  const int t = threadIdx.x, lane = t&63, wave = t>>6;
  const int rbase = blockIdx.x*16 + wave*4;
  float acc0=b[lane], acc1=acc0, acc2=acc0, acc3=acc0;
  for(int kt=0; kt<TOK; kt+=64){
    __syncthreads();
    #pragma unroll
    for(int i=0;i<4;i++){
      int f = t + 256*i;                     // 1024 float4s
      int kk = f>>4, c4 = (f&15)*4;
      *(float4*)&ws[kk][c4] = *(const float4*)&w[(size_t)(kt+kk)*Dd + c4];
    }
    __syncthreads();
    #pragma unroll 4
    for(int k=0;k<64;k+=4){
      float4 x0 = *(const float4*)&A[(size_t)(rbase+0)*TOK + kt + k];
      float4 x1 = *(const float4*)&A[(size_t)(rbase+1)*TOK + kt + k];
      float4 x2 = *(const float4*)&A[(size_t)(rbase+2)*TOK + kt + k];
      float4 x3 = *(const float4*)&A[(size_t)(rbase+3)*TOK + kt + k];
      #pragma unroll
      for(int j=0;j<4;j++){
        float wv = ws[k+j][lane];
        acc0 += ((const float*)&x0)[j]*wv;
        acc1 += ((const float*)&x1)[j]*wv;
        acc2 += ((const float*)&x2)[j]*wv;
        acc3 += ((const float*)&x3)[j]*wv;
      }
    }
  }
  x[(size_t)(rbase+0)*Dd + lane] = acc0;
  x[(size_t)(rbase+1)*Dd + lane] = acc1;
  x[(size_t)(rbase+2)*Dd + lane] = acc2;
  x[(size_t)(rbase+3)*Dd + lane] = acc3;
}

// x[T:M] = kg_emb[node_ids]  (float4 gather)
__global__ void k_nodes(const int* __restrict__ ids, const float* __restrict__ kg,
                        float* __restrict__ x){
  int t = blockIdx.x*256 + threadIdx.x;      // N*16 threads
  int i = t>>4, c = t&15;
  ((float4*)x)[(size_t)(Tt+i)*16 + c] = ((const float4*)kg)[(size_t)ids[i]*16 + c];
}

// relid from one-hot rows: coalesced float4 scan of all E*R values
__global__ void k_relid(const float* __restrict__ ea, int* __restrict__ relid){
  int t = blockIdx.x*256 + threadIdx.x;
  size_t g4 = (size_t)t*4;
  if(g4 >= (size_t)Ee*Rr) return;
  float4 v = *(const float4*)&ea[g4];
  #pragma unroll
  for(int j=0;j<4;j++){
    if(((const float*)&v)[j] > 0.5f){
      unsigned g = (unsigned)(g4 + j);
      unsigned e = g / 50u;
      relid[e] = (int)(g - e*50u);
    }
  }
}

// W[r] = relu(rel_emb[r] @ w_e2 + b_e2), flat [r*4096 + d*64 + o]
__global__ void k_W(const float* __restrict__ rel, const float* __restrict__ w2,
                    const float* __restrict__ b2, float* __restrict__ W){
  int t = blockIdx.x*256 + threadIdx.x;      // R*4096 threads
  int r = t>>12, j = t&4095;
  float acc = b2[j];
  const float* rp = rel + r*Dd;
  #pragma unroll 8
  for(int d=0;d<Dd;d++) acc += rp[d] * w2[(size_t)d*4096 + j];
  W[t] = acc > 0.f ? acc : 0.f;
}

// u_r[d] = sum_o W[r][d][o] * att_w[64+o]  (both layers)
__global__ void k_U(const float* __restrict__ W, const float* __restrict__ a1w,
                    const float* __restrict__ a2w, float* __restrict__ U1,
                    float* __restrict__ U2){
  int t = blockIdx.x*256 + threadIdx.x;      // R*64
  if(t >= Rr*Dd) return;
  const float* wp = W + (size_t)(t>>6)*4096 + (size_t)(t&63)*Dd;
  float s1 = 0.f, s2 = 0.f;
  #pragma unroll 8
  for(int o=0;o<Dd;o++){ float w = wp[o]; s1 += w*a1w[Dd+o]; s2 += w*a2w[Dd+o]; }
  U1[t] = s1; U2[t] = s2;
}

// Fused: y = relu?(x) @ root + bias   AND   p[i] = relu?(x[i]) . aw[0:64]
// 16 rows/block, 4 rows/wave; root staged in LDS once.
__global__ __launch_bounds__(256) void k_rootp(const float* __restrict__ x,
    const float* __restrict__ root, const float* __restrict__ bias,
    const float* __restrict__ aw, float* __restrict__ y, float* __restrict__ p,
    int dorelu){
  __shared__ float rs[Dd][Dd];
  const int t = threadIdx.x, lane = t&63, wave = t>>6;
  const int rbase = blockIdx.x*16 + wave*4;
  #pragma unroll
  for(int i=0;i<4;i++){
    int f = t + 256*i;
    int kk = f>>4, c4 = (f&15)*4;
    *(float4*)&rs[kk][c4] = *(const float4*)&root[(size_t)kk*Dd + c4];
  }
  __syncthreads();
  float acc0=bias[lane], acc1=acc0, acc2=acc0, acc3=acc0;
  #pragma unroll 4
  for(int k=0;k<64;k+=4){
    float4 x0 = *(const float4*)&x[(size_t)(rbase+0)*Dd + k];
    float4 x1 = *(const float4*)&x[(size_t)(rbase+1)*Dd + k];
    float4 x2 = *(const float4*)&x[(size_t)(rbase+2)*Dd + k];
    float4 x3 = *(const float4*)&x[(size_t)(rbase+3)*Dd + k];
    if(dorelu){ x0=relu4(x0); x1=relu4(x1); x2=relu4(x2); x3=relu4(x3); }
    #pragma unroll
    for(int j=0;j<4;j++){
      float wv = rs[k+j][lane];
      acc0 += ((const float*)&x0)[j]*wv;
      acc1 += ((const float*)&x1)[j]*wv;
      acc2 += ((const float*)&x2)[j]*wv;
      acc3 += ((const float*)&x3)[j]*wv;
    }
  }
  y[(size_t)(rbase+0)*Dd + lane] = acc0;
  y[(size_t)(rbase+1)*Dd + lane] = acc1;
  y[(size_t)(rbase+2)*Dd + lane] = acc2;
  y[(size_t)(rbase+3)*Dd + lane] = acc3;
  // attention p per row
  float av = aw[lane];
  #pragma unroll
  for(int i=0;i<4;i++){
    float xl = x[(size_t)(rbase+i)*Dd + lane];
    if(dorelu) xl = fmaxf(xl, 0.f);
    float pv = waveRed(xl*av);
    if(lane==0) p[rbase+i] = pv;
  }
}

// expa[e] = exp(p[dst] + relu?(x[src]).u_rel + att_b); block partial sums
__global__ void k_att(const float* __restrict__ x, const int* __restrict__ ei,
                      const int* __restrict__ relid, const float* __restrict__ U,
                      const float* __restrict__ p, const float* __restrict__ ab,
                      float* __restrict__ expa, float* __restrict__ part, int dorelu){
  __shared__ float sw[4];
  int wid = threadIdx.x>>6, lane = threadIdx.x&63;
  int e = blockIdx.x*4 + wid;                // 25000 blocks exactly
  int src = ei[e], dst = ei[Ee+e], r = relid[e];
  float xv = x[(size_t)src*Dd + lane];
  if(dorelu) xv = fmaxf(xv, 0.f);
  float v = waveRed(xv * U[r*Dd + lane]);
  if(lane==0){
    float ex = expf(v + p[dst] + ab[0]);
    expa[e] = ex;
    sw[wid] = ex;
  }
  __syncthreads();
  if(threadIdx.x==0) part[blockIdx.x] = sw[0]+sw[1]+sw[2]+sw[3];
}

__global__ void k_redsum(const float* __restrict__ part, int n, float* __restrict__ out){
  __shared__ float sr[4];
  float s = 0.f;
  for(int i=threadIdx.x;i<n;i+=256) s += part[i];
  s = waveRed(s);
  if((threadIdx.x&63)==0) sr[threadIdx.x>>6] = s;
  __syncthreads();
  if(threadIdx.x==0) out[0] = sr[0]+sr[1]+sr[2]+sr[3];
}

// y[dst] += relu?(x[src]) * (expa[e]/S)
__global__ void k_scatter(const float* __restrict__ x, const int* __restrict__ ei,
                          const float* __restrict__ expa, const float* __restrict__ S,
                          float* __restrict__ y, int dorelu){
  int wid = threadIdx.x>>6, lane = threadIdx.x&63;
  int e = blockIdx.x*4 + wid;
  float alpha = expa[e] / S[0];
  int src = ei[e], dst = ei[Ee+e];
  float xv = x[(size_t)src*Dd + lane];
  if(dorelu) xv = fmaxf(xv, 0.f);
  atomicAdd(&y[(size_t)dst*Dd + lane], xv*alpha);
}

// out = fx @ w_lin2 + b_lin2, tiled 32x128, 4x4 register block
__global__ __launch_bounds__(256) void k_out(const float* __restrict__ fx,
    const float* __restrict__ w, const float* __restrict__ b, float* __restrict__ out){
  __shared__ float aT[Dd][36];               // [k][r], padded for float4 align
  __shared__ float ws[Dd][128];
  const int t = threadIdx.x;
  const int r0 = blockIdx.x*32, co = blockIdx.y*128;
  #pragma unroll
  for(int i=0;i<2;i++){
    int f = t + 256*i;                       // 512 float4s (32x64 A-tile)
    int r = f>>4, k4 = (f&15)*4;
    float4 v = *(const float4*)&fx[(size_t)(r0+r)*Dd + k4];
    aT[k4+0][r]=v.x; aT[k4+1][r]=v.y; aT[k4+2][r]=v.z; aT[k4+3][r]=v.w;
  }
  #pragma unroll
  for(int i=0;i<8;i++){
    int f = t + 256*i;                       // 2048 float4s (64x128 W-tile)
    int kk = f>>5, c4 = (f&31)*4;
    *(float4*)&ws[kk][c4] = *(const float4*)&w[(size_t)kk*TOK + co + c4];
  }
  __syncthreads();
  const int tr = t>>5, tc = t&31;
  const int rb = tr*4, cb = tc*4;
  float4 bv = *(const float4*)&b[co+cb];
  float acc[4][4];
  #pragma unroll
  for(int i=0;i<4;i++){
    acc[i][0]=bv.x; acc[i][1]=bv.y; acc[i][2]=bv.z; acc[i][3]=bv.w;
  }
  #pragma unroll 8
  for(int k=0;k<Dd;k++){
    float4 a  = *(const float4*)&aT[k][rb];
    float4 wv = *(const float4*)&ws[k][cb];
    #pragma unroll
    for(int i=0;i<4;i++){
      float av = ((const float*)&a)[i];
      acc[i][0] += av*wv.x; acc[i][1] += av*wv.y;
      acc[i][2] += av*wv.z; acc[i][3] += av*wv.w;
    }
  }
  #pragma unroll
  for(int i=0;i<4;i++){
    float4 o; o.x=acc[i][0]; o.y=acc[i][1]; o.z=acc[i][2]; o.w=acc[i][3];
    *(float4*)&out[(size_t)(r0+rb+i)*TOK + co + cb] = o;
  }
}

// masked MSE partials over edges
__global__ void k_kge(const float* __restrict__ fx, const int* __restrict__ ei,
                      const int* __restrict__ relid, const float* __restrict__ rel,
                      float* __restrict__ part){
  __shared__ float sr[4];
  int wid = threadIdx.x>>6, lane = threadIdx.x&63;
  int gw = blockIdx.x*4 + wid;               // 512 blocks -> 2048 waves
  float acc = 0.f;
  for(int e=gw; e<Ee; e+=2048){
    int r = relid[e];
    if(r < 47){
      int src = ei[e], dst = ei[Ee+e];
      float d = fx[(size_t)src*Dd + lane] + rel[r*Dd + lane] - fx[(size_t)dst*Dd + lane];
      acc += d*d;
    }
  }
  acc = waveRed(acc);
  if(lane==0) sr[wid] = acc;
  __syncthreads();
  if(threadIdx.x==0) part[blockIdx.x] = sr[0]+sr[1]+sr[2]+sr[3];
}

// node-type CE partials
__global__ void k_nt(const float* __restrict__ fx, const int* __restrict__ lab,
                     const float* __restrict__ wnt, const float* __restrict__ bnt,
                     float* __restrict__ part){
  __shared__ float sr[4];
  int i = blockIdx.x*256 + threadIdx.x;
  float contrib = 0.f;
  if(i < Mm){
    const float* r = fx + (size_t)i*Dd;
    float l0 = bnt[0], l1 = bnt[1], l2 = bnt[2];
    #pragma unroll 8
    for(int k=0;k<Dd;k++){
      float f = r[k];
      l0 += f*wnt[k*3+0]; l1 += f*wnt[k*3+1]; l2 += f*wnt[k*3+2];
    }
    float mx = fmaxf(l0, fmaxf(l1,l2));
    float lse = logf(expf(l0-mx)+expf(l1-mx)+expf(l2-mx)) + mx;
    int lb = lab[i];
    float lp = (lb==0 ? l0 : (lb==1 ? l1 : l2)) - lse;
    contrib = -lp;
  }
  float s = waveRed(contrib);
  if((threadIdx.x&63)==0) sr[threadIdx.x>>6] = s;
  __syncthreads();
  if(threadIdx.x==0) part[blockIdx.x] = sr[0]+sr[1]+sr[2]+sr[3];
}

// reduce loss partials -> out[M*TOK], out[M*TOK+1]
__global__ void k_final(const float* __restrict__ kgep, const float* __restrict__ ntp,
                        float* __restrict__ out){
  __shared__ float sa[4], sb[4];
  float s = 0.f, t = 0.f;
  for(int i=threadIdx.x;i<512;i+=256) s += kgep[i];
  for(int i=threadIdx.x;i<95;i+=256)  t += ntp[i];
  s = waveRed(s); t = waveRed(t);
  if((threadIdx.x&63)==0){ sa[threadIdx.x>>6] = s; sb[threadIdx.x>>6] = t; }
  __syncthreads();
  if(threadIdx.x==0){
    size_t base = (size_t)Mm*TOK;
    out[base+0] = (sa[0]+sa[1]+sa[2]+sa[3]) / (float)(Ee*Dd);
    out[base+1] = (sb[0]+sb[1]+sb[2]+sb[3]) / (float)Mm;
  }
}

extern "C" void kernel_launch(void* const* d_in, const int* in_sizes, int n_in,
                              void* d_out, int out_size, void* d_ws, size_t ws_size,
                              hipStream_t stream) {
  const int*   node_ids = (const int*)d_in[0];
  const int*   ei       = (const int*)d_in[1];
  const float* eattr    = (const float*)d_in[2];
  const float* tokemb   = (const float*)d_in[3];
  const int*   labels   = (const int*)d_in[4];
  const float* kg       = (const float*)d_in[5];
  const float* rel      = (const float*)d_in[6];
  const float* w_e2     = (const float*)d_in[7];
  const float* b_e2     = (const float*)d_in[8];
  const float* a1w      = (const float*)d_in[9];
  const float* a1b      = (const float*)d_in[10];
  const float* root1    = (const float*)d_in[11];
  const float* bias1    = (const float*)d_in[12];
  const float* a2w      = (const float*)d_in[13];
  const float* a2b      = (const float*)d_in[14];
  const float* root2    = (const float*)d_in[15];
  const float* bias2    = (const float*)d_in[16];
  const float* wlin1    = (const float*)d_in[17];
  const float* blin1    = (const float*)d_in[18];
  const float* wlin2    = (const float*)d_in[19];
  const float* blin2    = (const float*)d_in[20];
  const float* wnt      = (const float*)d_in[21];
  const float* bnt      = (const float*)d_in[22];

  float* ws = (float*)d_ws;
  float* x    = ws;                       // M*64
  float* h    = x  + (size_t)Mm*Dd;       // M*64
  float* fx   = h  + (size_t)Mm*Dd;       // M*64
  float* W    = fx + (size_t)Mm*Dd;       // 50*4096
  float* U1   = W  + Rr*4096;             // 3200
  float* U2   = U1 + Rr*Dd;               // 3200
  float* expa = U2 + Rr*Dd;               // E
  float* p    = expa + Ee;                // M
  int*   relid= (int*)(p + Mm);           // E
  float* part = (float*)(relid + Ee);     // 25000
  float* kgep = part + 25000;             // 512
  float* ntp  = kgep + 512;               // 95 (pad 128)
  float* red  = ntp + 128;                // 2
  float* out  = (float*)d_out;

  // ---- stage 0 ----
  k_tok  <<<Tt/16, 256, 0, stream>>>(tokemb, wlin1, blin1, x);
  k_nodes<<<Nn*16/256, 256, 0, stream>>>(node_ids, kg, x);
  k_relid<<<(Ee*Rr/4 + 255)/256, 256, 0, stream>>>(eattr, relid);
  k_W    <<<Rr*4096/256, 256, 0, stream>>>(rel, w_e2, b_e2, W);
  k_U    <<<(Rr*Dd+255)/256, 256, 0, stream>>>(W, a1w, a2w, U1, U2);

  // ---- layer 1: x -> h ----
  k_rootp  <<<Mm/16, 256, 0, stream>>>(x, root1, bias1, a1w, h, p, 0);
  k_att    <<<Ee/4, 256, 0, stream>>>(x, ei, relid, U1, p, a1b, expa, part, 0);
  k_redsum <<<1, 256, 0, stream>>>(part, Ee/4, red);
  k_scatter<<<Ee/4, 256, 0, stream>>>(x, ei, expa, red, h, 0);

  // ---- layer 2: relu(h) -> fx ----
  k_rootp  <<<Mm/16, 256, 0, stream>>>(h, root2, bias2, a2w, fx, p, 1);
  k_att    <<<Ee/4, 256, 0, stream>>>(h, ei, relid, U2, p, a2b, expa, part, 1);
  k_redsum <<<1, 256, 0, stream>>>(part, Ee/4, red+1);
  k_scatter<<<Ee/4, 256, 0, stream>>>(h, ei, expa, red+1, fx, 1);

  // ---- outputs ----
  dim3 og(Mm/32, TOK/128);
  k_out  <<<og, 256, 0, stream>>>(fx, wlin2, blin2, out);
  k_kge  <<<512, 256, 0, stream>>>(fx, ei, relid, rel, kgep);
  k_nt   <<<(Mm+255)/256, 256, 0, stream>>>(fx, labels, wnt, bnt, ntp);
  k_final<<<1, 256, 0, stream>>>(kgep, ntp, out);
}